// Round 1
// baseline (481.542 us; speedup 1.0000x reference)
//
#include <hip/hip_runtime.h>
#include <hip/hip_bf16.h>

// Shapes (fixed): B=8, H=W=32, E=768, nh=12, hd=64, N=1024, BH=96
// ws layout (bytes):
//   xb      @ 0         : 8192*768*2   = 12,582,912  (x cast to bf16)
//   wqkvT   @ 12582912   : 2304*768*2  =  3,538,944  (Wqkv^T bf16)
//   wprojT  @ 16121856   : 768*768*2   =  1,179,648  (Wproj^T bf16)
//   qkvb    @ 17301504   : 8192*2304*2 = 37,748,736  (qkv bf16; later aliased by out_r 12.6MB)
//   Q       @ 55050240   : 96*1024*64*2 = 12,582,912
//   K       @ 67633152   : 12,582,912
//   Vt      @ 80216064   : 12,582,912  (V transposed: [bh][d][n])
// total ~92.8 MB

typedef __attribute__((ext_vector_type(8))) short short8;
typedef __attribute__((ext_vector_type(4))) float f32x4;

__global__ __launch_bounds__(256) void cast_f32_bf16(const float* __restrict__ in,
                                                     __hip_bfloat16* __restrict__ out) {
  int i = (blockIdx.x * 256 + threadIdx.x) * 4;
  float4 v = *(const float4*)&in[i];
  out[i + 0] = __float2bfloat16(v.x);
  out[i + 1] = __float2bfloat16(v.y);
  out[i + 2] = __float2bfloat16(v.z);
  out[i + 3] = __float2bfloat16(v.w);
}

// in [K][N] f32 -> out [N][K] bf16
__global__ __launch_bounds__(256) void transpose_cast(const float* __restrict__ in,
                                                      __hip_bfloat16* __restrict__ out,
                                                      int K, int N) {
  __shared__ float tile[32][33];
  int n0 = blockIdx.x * 32, k0 = blockIdx.y * 32;
  int tx = threadIdx.x & 31, ty = threadIdx.x >> 5;  // 32 x 8
#pragma unroll
  for (int i = 0; i < 4; ++i)
    tile[ty + i * 8][tx] = in[(size_t)(k0 + ty + i * 8) * N + n0 + tx];
  __syncthreads();
#pragma unroll
  for (int i = 0; i < 4; ++i)
    out[(size_t)(n0 + ty + i * 8) * K + k0 + tx] = __float2bfloat16(tile[tx][ty + i * 8]);
}

// C[M,N] = A[M,K] * Bt[N,K]^T + bias ; 128x128 tile, 4 waves (2x2), BK=64
template<bool OUT_BF16>
__global__ __launch_bounds__(256) void gemm_bt(const __hip_bfloat16* __restrict__ A,
                                               const __hip_bfloat16* __restrict__ Bt,
                                               const float* __restrict__ bias,
                                               void* __restrict__ Cout,
                                               int N, int K) {
  __shared__ __hip_bfloat16 Al[128][72];  // +8 pad -> 2-way bank alias (free)
  __shared__ __hip_bfloat16 Bl[128][72];
  int n0 = blockIdx.x * 128, m0 = blockIdx.y * 128;
  int tid = threadIdx.x, lane = tid & 63, wid = tid >> 6;
  int wm = wid >> 1, wn = wid & 1;
  int lr = lane & 15, lg = lane >> 4;
  f32x4 acc[4][4] = {};
  for (int k0 = 0; k0 < K; k0 += 64) {
#pragma unroll
    for (int i = 0; i < 4; ++i) {
      int chunk = tid + 256 * i;            // 1024 chunks of 16B
      int row = chunk >> 3, coff = (chunk & 7) * 8;
      *(short8*)&Al[row][coff] = *(const short8*)&A[(size_t)(m0 + row) * K + k0 + coff];
      *(short8*)&Bl[row][coff] = *(const short8*)&Bt[(size_t)(n0 + row) * K + k0 + coff];
    }
    __syncthreads();
#pragma unroll
    for (int ks = 0; ks < 2; ++ks) {
      short8 af[4], bfr[4];
#pragma unroll
      for (int m = 0; m < 4; ++m)
        af[m] = *(const short8*)&Al[wm * 64 + m * 16 + lr][ks * 32 + lg * 8];
#pragma unroll
      for (int n = 0; n < 4; ++n)
        bfr[n] = *(const short8*)&Bl[wn * 64 + n * 16 + lr][ks * 32 + lg * 8];
#pragma unroll
      for (int m = 0; m < 4; ++m)
#pragma unroll
        for (int n = 0; n < 4; ++n)
          acc[m][n] = __builtin_amdgcn_mfma_f32_16x16x32_bf16(af[m], bfr[n], acc[m][n], 0, 0, 0);
    }
    __syncthreads();
  }
#pragma unroll
  for (int n = 0; n < 4; ++n) {
    int col = n0 + wn * 64 + n * 16 + lr;
    float bv = bias[col];
#pragma unroll
    for (int m = 0; m < 4; ++m) {
      int rowb = m0 + wm * 64 + m * 16 + lg * 4;
#pragma unroll
      for (int r = 0; r < 4; ++r) {
        float v = acc[m][n][r] + bv;
        if (OUT_BF16)
          ((__hip_bfloat16*)Cout)[(size_t)(rowb + r) * N + col] = __float2bfloat16(v);
        else
          ((float*)Cout)[(size_t)(rowb + r) * N + col] = v;
      }
    }
  }
}

// Faithful scrambled qkv extraction:
// q/k/v[bh,n2,d2] (c2=0/1/2):  F = bh*196608 + n2*192 + d2*3 + c2
//   b=F/2359296; G=F%2359296; n=G/2304; G2=G%2304; h=G2/192; G3=G2%192; c=G3>>6; dd=G3&63
//   src = qkv[(b*1024+n)*2304 + h*192 + dd*3 + c]
__global__ __launch_bounds__(256) void permute_qkv(const __hip_bfloat16* __restrict__ qkv,
                                                   __hip_bfloat16* __restrict__ Q,
                                                   __hip_bfloat16* __restrict__ Kd,
                                                   __hip_bfloat16* __restrict__ Vt) {
  int bh = blockIdx.y;
  int n0 = blockIdx.x * 64;
  int tid = threadIdx.x;
  __shared__ __hip_bfloat16 vt[64][72];
#pragma unroll
  for (int i = 0; i < 16; ++i) {
    int idx = tid + i * 256;  // 0..4095 over (n_local, d2)
    int nl = idx >> 6, d2 = idx & 63;
    int n2 = n0 + nl;
    int F = bh * 196608 + n2 * 192 + d2 * 3;
#pragma unroll
    for (int c2 = 0; c2 < 3; ++c2) {
      int Fc = F + c2;
      int b = Fc / 2359296;
      int G = Fc % 2359296;
      int n = G / 2304, G2 = G % 2304;
      int h = G2 / 192, G3 = G2 % 192;
      int c = G3 >> 6, dd = G3 & 63;
      __hip_bfloat16 v = qkv[(size_t)(b * 1024 + n) * 2304 + h * 192 + dd * 3 + c];
      if (c2 == 0)      Q[(size_t)bh * 65536 + n2 * 64 + d2] = v;
      else if (c2 == 1) Kd[(size_t)bh * 65536 + n2 * 64 + d2] = v;
      else              vt[d2][nl] = v;
    }
  }
  __syncthreads();
#pragma unroll
  for (int i = 0; i < 16; ++i) {
    int idx = tid + i * 256;
    int d2 = idx >> 6, nl = idx & 63;
    Vt[(size_t)bh * 65536 + d2 * 1024 + n0 + nl] = vt[d2][nl];
  }
}

// Flash attention, 4 waves x 16 q-rows, KV chunks of 64.
// Writes output bf16 with the faithful out-permutation applied (feeds GEMM2).
__global__ __launch_bounds__(256) void attn_kernel(const __hip_bfloat16* __restrict__ Q,
                                                   const __hip_bfloat16* __restrict__ Kd,
                                                   const __hip_bfloat16* __restrict__ Vt,
                                                   const float* __restrict__ rph,
                                                   const float* __restrict__ rpw,
                                                   __hip_bfloat16* __restrict__ outp) {
  int bh = blockIdx.y, qt = blockIdx.x;
  int tid = threadIdx.x, lane = tid & 63, w = tid >> 6;
  int lr = lane & 15, lg = lane >> 4;
  __shared__ float rh[64][32];
  __shared__ float rw[64][32];
  __shared__ __hip_bfloat16 pl[4][16][72];
  const __hip_bfloat16* Qb = Q + (size_t)bh * 65536;
  const __hip_bfloat16* Kb = Kd + (size_t)bh * 65536;
  const __hip_bfloat16* Vb = Vt + (size_t)bh * 65536;

  // rel-pos bias tables for this Q tile (uses UNSCALED q, per reference)
  for (int i = tid; i < 4096; i += 256) {
    int which = i >> 11;
    int rl = (i & 2047) >> 5, kk = i & 31;
    int n2 = qt * 64 + rl;
    int hq = n2 >> 5, wq = n2 & 31;
    const float* tab = which ? rpw + (size_t)(wq - kk + 31) * 64
                             : rph + (size_t)(hq - kk + 31) * 64;
    const __hip_bfloat16* qrow = Qb + (size_t)n2 * 64;
    float s = 0.f;
#pragma unroll
    for (int d = 0; d < 64; ++d) s += __bfloat162float(qrow[d]) * tab[d];
    if (which) rw[rl][kk] = s;
    else       rh[rl][kk] = s;
  }
  __syncthreads();

  int qrow0 = qt * 64 + w * 16;
  short8 qf0 = *(const short8*)&Qb[(size_t)(qrow0 + lr) * 64 + lg * 8];
  short8 qf1 = *(const short8*)&Qb[(size_t)(qrow0 + lr) * 64 + 32 + lg * 8];
  f32x4 O[4] = {};
  float mrun[4], lrun[4];
#pragma unroll
  for (int r = 0; r < 4; ++r) { mrun[r] = -1e30f; lrun[r] = 0.f; }

  for (int kv0 = 0; kv0 < 1024; kv0 += 64) {
    f32x4 S[4];
#pragma unroll
    for (int t = 0; t < 4; ++t) {
      short8 kf0 = *(const short8*)&Kb[(size_t)(kv0 + t * 16 + lr) * 64 + lg * 8];
      short8 kf1 = *(const short8*)&Kb[(size_t)(kv0 + t * 16 + lr) * 64 + 32 + lg * 8];
      f32x4 z = {};
      z = __builtin_amdgcn_mfma_f32_16x16x32_bf16(qf0, kf0, z, 0, 0, 0);
      z = __builtin_amdgcn_mfma_f32_16x16x32_bf16(qf1, kf1, z, 0, 0, 0);
      S[t] = z;
    }
    int rlb = w * 16 + lg * 4;
    float p[4][4];
#pragma unroll
    for (int r = 0; r < 4; ++r) {
      float mx = -1e30f;
#pragma unroll
      for (int t = 0; t < 4; ++t) {
        int kv = kv0 + t * 16 + lr;
        float sv = S[t][r] * 0.125f + rh[rlb + r][kv >> 5] + rw[rlb + r][kv & 31];
        p[t][r] = sv;
        mx = fmaxf(mx, sv);
      }
#pragma unroll
      for (int msk = 1; msk < 16; msk <<= 1) mx = fmaxf(mx, __shfl_xor(mx, msk, 64));
      float mnew = fmaxf(mrun[r], mx);
      float alpha = __expf(mrun[r] - mnew);
      float sm = 0.f;
#pragma unroll
      for (int t = 0; t < 4; ++t) {
        float e = __expf(p[t][r] - mnew);
        p[t][r] = e;
        sm += e;
      }
#pragma unroll
      for (int msk = 1; msk < 16; msk <<= 1) sm += __shfl_xor(sm, msk, 64);
      lrun[r] = lrun[r] * alpha + sm;
      mrun[r] = mnew;
#pragma unroll
      for (int dt = 0; dt < 4; ++dt) O[dt][r] *= alpha;
    }
    __syncthreads();  // WAR: previous iteration's pl reads done
#pragma unroll
    for (int t = 0; t < 4; ++t)
#pragma unroll
      for (int r = 0; r < 4; ++r)
        pl[w][lg * 4 + r][t * 16 + lr] = __float2bfloat16(p[t][r]);
    __syncthreads();  // RAW: pl visible
    short8 pf0 = *(const short8*)&pl[w][lr][lg * 8];
    short8 pf1 = *(const short8*)&pl[w][lr][32 + lg * 8];
#pragma unroll
    for (int dt = 0; dt < 4; ++dt) {
      short8 vf0 = *(const short8*)&Vb[(size_t)(dt * 16 + lr) * 1024 + kv0 + lg * 8];
      short8 vf1 = *(const short8*)&Vb[(size_t)(dt * 16 + lr) * 1024 + kv0 + 32 + lg * 8];
      O[dt] = __builtin_amdgcn_mfma_f32_16x16x32_bf16(pf0, vf0, O[dt], 0, 0, 0);
      O[dt] = __builtin_amdgcn_mfma_f32_16x16x32_bf16(pf1, vf1, O[dt], 0, 0, 0);
    }
  }

  // faithful out permutation: S=bh*65536+n*64+d -> (b,p,q,j,dd) -> P
#pragma unroll
  for (int r = 0; r < 4; ++r) {
    float inv = 1.f / lrun[r];
    int n = qrow0 + lg * 4 + r;
#pragma unroll
    for (int dt = 0; dt < 4; ++dt) {
      int d = dt * 16 + lr;
      int Sidx = bh * 65536 + n * 64 + d;
      int b = Sidx / 786432, r1 = Sidx % 786432;
      int pp = r1 / 24576, r2 = r1 % 24576;
      int qq = r2 / 768, r3 = r2 % 768;
      int j = r3 >> 6, dd = r3 & 63;
      int P = b * 786432 + j * 65536 + pp * 2048 + qq * 64 + dd;
      outp[P] = __float2bfloat16(O[dt][r] * inv);
    }
  }
}

extern "C" void kernel_launch(void* const* d_in, const int* in_sizes, int n_in,
                              void* d_out, int out_size, void* d_ws, size_t ws_size,
                              hipStream_t stream) {
  const float* x     = (const float*)d_in[0];
  const float* Wqkv  = (const float*)d_in[1];
  const float* bqkv  = (const float*)d_in[2];
  const float* Wproj = (const float*)d_in[3];
  const float* bproj = (const float*)d_in[4];
  const float* rph   = (const float*)d_in[5];
  const float* rpw   = (const float*)d_in[6];
  float* out = (float*)d_out;
  char* ws = (char*)d_ws;

  __hip_bfloat16* xb     = (__hip_bfloat16*)(ws);
  __hip_bfloat16* wqkvT  = (__hip_bfloat16*)(ws + 12582912);
  __hip_bfloat16* wprojT = (__hip_bfloat16*)(ws + 16121856);
  __hip_bfloat16* qkvb   = (__hip_bfloat16*)(ws + 17301504);  // later aliased as out_r
  __hip_bfloat16* Qm     = (__hip_bfloat16*)(ws + 55050240);
  __hip_bfloat16* Km     = (__hip_bfloat16*)(ws + 67633152);
  __hip_bfloat16* Vtm    = (__hip_bfloat16*)(ws + 80216064);

  cast_f32_bf16<<<dim3(6144), dim3(256), 0, stream>>>(x, xb);
  transpose_cast<<<dim3(72, 24), dim3(256), 0, stream>>>(Wqkv, wqkvT, 768, 2304);
  transpose_cast<<<dim3(24, 24), dim3(256), 0, stream>>>(Wproj, wprojT, 768, 768);
  gemm_bt<true><<<dim3(18, 64), dim3(256), 0, stream>>>(xb, wqkvT, bqkv, (void*)qkvb, 2304, 768);
  permute_qkv<<<dim3(16, 96), dim3(256), 0, stream>>>(qkvb, Qm, Km, Vtm);
  attn_kernel<<<dim3(16, 96), dim3(256), 0, stream>>>(Qm, Km, Vtm, rph, rpw, qkvb);
  gemm_bt<false><<<dim3(6, 64), dim3(256), 0, stream>>>(qkvb, wprojT, bproj, (void*)out, 768, 768);
}

// Round 2
// 258.416 us; speedup vs baseline: 1.8634x; 1.8634x over previous
//
#include <hip/hip_runtime.h>
#include <hip/hip_bf16.h>

// Shapes (fixed): B=8, H=W=32, E=768, nh=12, hd=64, N=1024, BH=96
// ws layout (bytes):
//   xb      @ 0          : 12,582,912  (x cast to bf16)
//   wqkvT   @ 12582912   :  3,538,944  (Wqkv^T bf16)
//   wprojT  @ 16121856   :  1,179,648  (Wproj^T bf16)
//   qkvb    @ 17301504   : 37,748,736  (qkv bf16; later aliased by attn-out bf16)
//   Q       @ 55050240   : 12,582,912
//   K       @ 67633152   : 12,582,912
//   Vt      @ 80216064   : 12,582,912  (V transposed: [bh][d][n])

typedef __attribute__((ext_vector_type(8))) short short8;
typedef __attribute__((ext_vector_type(4))) float f32x4;

__global__ __launch_bounds__(256) void cast_f32_bf16(const float* __restrict__ in,
                                                     __hip_bfloat16* __restrict__ out) {
  int i = (blockIdx.x * 256 + threadIdx.x) * 4;
  float4 v = *(const float4*)&in[i];
  out[i + 0] = __float2bfloat16(v.x);
  out[i + 1] = __float2bfloat16(v.y);
  out[i + 2] = __float2bfloat16(v.z);
  out[i + 3] = __float2bfloat16(v.w);
}

// in [K][N] f32 -> out [N][K] bf16
__global__ __launch_bounds__(256) void transpose_cast(const float* __restrict__ in,
                                                      __hip_bfloat16* __restrict__ out,
                                                      int K, int N) {
  __shared__ float tile[32][33];
  int n0 = blockIdx.x * 32, k0 = blockIdx.y * 32;
  int tx = threadIdx.x & 31, ty = threadIdx.x >> 5;  // 32 x 8
#pragma unroll
  for (int i = 0; i < 4; ++i)
    tile[ty + i * 8][tx] = in[(size_t)(k0 + ty + i * 8) * N + n0 + tx];
  __syncthreads();
#pragma unroll
  for (int i = 0; i < 4; ++i)
    out[(size_t)(n0 + ty + i * 8) * K + k0 + tx] = __float2bfloat16(tile[tx][ty + i * 8]);
}

// C[M,N] = A[M,K] * Bt[N,K]^T + bias ; 128x128 tile, 4 waves (2x2), BK=64
template<bool OUT_BF16>
__global__ __launch_bounds__(256) void gemm_bt(const __hip_bfloat16* __restrict__ A,
                                               const __hip_bfloat16* __restrict__ Bt,
                                               const float* __restrict__ bias,
                                               void* __restrict__ Cout,
                                               int N, int K) {
  __shared__ __hip_bfloat16 Al[128][72];
  __shared__ __hip_bfloat16 Bl[128][72];
  int n0 = blockIdx.x * 128, m0 = blockIdx.y * 128;
  int tid = threadIdx.x, lane = tid & 63, wid = tid >> 6;
  int wm = wid >> 1, wn = wid & 1;
  int lr = lane & 15, lg = lane >> 4;
  f32x4 acc[4][4] = {};
  for (int k0 = 0; k0 < K; k0 += 64) {
#pragma unroll
    for (int i = 0; i < 4; ++i) {
      int chunk = tid + 256 * i;
      int row = chunk >> 3, coff = (chunk & 7) * 8;
      *(short8*)&Al[row][coff] = *(const short8*)&A[(size_t)(m0 + row) * K + k0 + coff];
      *(short8*)&Bl[row][coff] = *(const short8*)&Bt[(size_t)(n0 + row) * K + k0 + coff];
    }
    __syncthreads();
#pragma unroll
    for (int ks = 0; ks < 2; ++ks) {
      short8 af[4], bfr[4];
#pragma unroll
      for (int m = 0; m < 4; ++m)
        af[m] = *(const short8*)&Al[wm * 64 + m * 16 + lr][ks * 32 + lg * 8];
#pragma unroll
      for (int n = 0; n < 4; ++n)
        bfr[n] = *(const short8*)&Bl[wn * 64 + n * 16 + lr][ks * 32 + lg * 8];
#pragma unroll
      for (int m = 0; m < 4; ++m)
#pragma unroll
        for (int n = 0; n < 4; ++n)
          acc[m][n] = __builtin_amdgcn_mfma_f32_16x16x32_bf16(af[m], bfr[n], acc[m][n], 0, 0, 0);
    }
    __syncthreads();
  }
#pragma unroll
  for (int n = 0; n < 4; ++n) {
    int col = n0 + wn * 64 + n * 16 + lr;
    float bv = bias[col];
#pragma unroll
    for (int m = 0; m < 4; ++m) {
      int rowb = m0 + wm * 64 + m * 16 + lg * 4;
#pragma unroll
      for (int r = 0; r < 4; ++r) {
        float v = acc[m][n][r] + bv;
        if (OUT_BF16)
          ((__hip_bfloat16*)Cout)[(size_t)(rowb + r) * N + col] = __float2bfloat16(v);
        else
          ((float*)Cout)[(size_t)(rowb + r) * N + col] = v;
      }
    }
  }
}

// Faithful scrambled qkv extraction (verified in R0).
__global__ __launch_bounds__(256) void permute_qkv(const __hip_bfloat16* __restrict__ qkv,
                                                   __hip_bfloat16* __restrict__ Q,
                                                   __hip_bfloat16* __restrict__ Kd,
                                                   __hip_bfloat16* __restrict__ Vt) {
  int bh = blockIdx.y;
  int n0 = blockIdx.x * 64;
  int tid = threadIdx.x;
  __shared__ __hip_bfloat16 vt[64][72];
#pragma unroll
  for (int i = 0; i < 16; ++i) {
    int idx = tid + i * 256;
    int nl = idx >> 6, d2 = idx & 63;
    int n2 = n0 + nl;
    int F = bh * 196608 + n2 * 192 + d2 * 3;
#pragma unroll
    for (int c2 = 0; c2 < 3; ++c2) {
      int Fc = F + c2;
      int b = Fc / 2359296;
      int G = Fc % 2359296;
      int n = G / 2304, G2 = G % 2304;
      int h = G2 / 192, G3 = G2 % 192;
      int c = G3 >> 6, dd = G3 & 63;
      __hip_bfloat16 v = qkv[(size_t)(b * 1024 + n) * 2304 + h * 192 + dd * 3 + c];
      if (c2 == 0)      Q[(size_t)bh * 65536 + n2 * 64 + d2] = v;
      else if (c2 == 1) Kd[(size_t)bh * 65536 + n2 * 64 + d2] = v;
      else              vt[d2][nl] = v;
    }
  }
  __syncthreads();
#pragma unroll
  for (int i = 0; i < 16; ++i) {
    int idx = tid + i * 256;
    int d2 = idx >> 6, nl = idx & 63;
    Vt[(size_t)bh * 65536 + d2 * 1024 + n0 + nl] = vt[d2][nl];
  }
}

__device__ inline short8 cvt8(const float* p) {
  short8 r;
#pragma unroll
  for (int j = 0; j < 8; ++j) {
    __hip_bfloat16 b = __float2bfloat16(p[j]);
    r[j] = *reinterpret_cast<const short*>(&b);
  }
  return r;
}

// Flash attention v2: 1 wave/block, 32 q-rows/wave (2 q-tiles sharing K/V loads),
// swapped QK^T (S^T: lane holds one q-row's kv slice -> 2-shuffle row reduce),
// rel-pos bias via MFMA, XCD-swizzled grid (12 bh per XCD).
__global__ __launch_bounds__(64) void attn2(const __hip_bfloat16* __restrict__ Q,
                                            const __hip_bfloat16* __restrict__ Kd,
                                            const __hip_bfloat16* __restrict__ Vt,
                                            const float* __restrict__ rph,
                                            const float* __restrict__ rpw,
                                            __hip_bfloat16* __restrict__ outp) {
  int orig = blockIdx.x;             // 3072 = 96 bh * 32 qtiles
  int xcd = orig & 7, loc = orig >> 3;     // 384 per xcd
  int bh = xcd * 12 + (loc % 12);
  int qt = loc / 12;                       // 0..31
  int lane = threadIdx.x;
  int lr = lane & 15, lg = lane >> 4;

  __shared__ float rh_lds[32][33];         // rh[q_local][k]  k=0..31
  __shared__ char smem[8704];              // rwf[32][68] f32, later pl[2][16][72] bf16
  float (*rwf)[68] = (float (*)[68])smem;
  __hip_bfloat16 (*pl)[16][72] = (__hip_bfloat16 (*)[16][72])smem;

  const __hip_bfloat16* Qb = Q + (size_t)bh * 65536;
  const __hip_bfloat16* Kb = Kd + (size_t)bh * 65536;
  const __hip_bfloat16* Vb = Vt + (size_t)bh * 65536;

  int q0 = qt * 32;
  int hq = qt;  // (q0+r)>>5 for r<32

  // Q A-fragments for both 16-row tiles
  short8 qf[2][2];
#pragma unroll
  for (int qh = 0; qh < 2; ++qh) {
    qf[qh][0] = *(const short8*)&Qb[(size_t)(q0 + qh * 16 + lr) * 64 + lg * 8];
    qf[qh][1] = *(const short8*)&Qb[(size_t)(q0 + qh * 16 + lr) * 64 + 32 + lg * 8];
  }

  // ---- rel-pos bias via MFMA ----
  // rh[q][k] = dot(q_row, rph[hq - k + 31]) , k=0..31
#pragma unroll
  for (int kt = 0; kt < 2; ++kt) {
    int row = hq - (kt * 16 + lr) + 31;          // 0..62
    const float* tp = rph + (size_t)row * 64 + lg * 8;
    short8 th0 = cvt8(tp), th1 = cvt8(tp + 32);
#pragma unroll
    for (int qh = 0; qh < 2; ++qh) {
      f32x4 a = {};
      a = __builtin_amdgcn_mfma_f32_16x16x32_bf16(qf[qh][0], th0, a, 0, 0, 0);
      a = __builtin_amdgcn_mfma_f32_16x16x32_bf16(qf[qh][1], th1, a, 0, 0, 0);
#pragma unroll
      for (int r = 0; r < 4; ++r)
        rh_lds[qh * 16 + lg * 4 + r][kt * 16 + lr] = a[r];
    }
  }
  // rw full table: D2[q][j] = dot(q_row, rpw[j]), j=0..63
#pragma unroll
  for (int jt = 0; jt < 4; ++jt) {
    const float* tp = rpw + (size_t)(jt * 16 + lr) * 64 + lg * 8;
    short8 tw0 = cvt8(tp), tw1 = cvt8(tp + 32);
#pragma unroll
    for (int qh = 0; qh < 2; ++qh) {
      f32x4 a = {};
      a = __builtin_amdgcn_mfma_f32_16x16x32_bf16(qf[qh][0], tw0, a, 0, 0, 0);
      a = __builtin_amdgcn_mfma_f32_16x16x32_bf16(qf[qh][1], tw1, a, 0, 0, 0);
#pragma unroll
      for (int r = 0; r < 4; ++r)
        rwf[qh * 16 + lg * 4 + r][jt * 16 + lr] = a[r];
    }
  }
  __syncthreads();
  // gather per-lane rw registers: this lane covers q_local = qh*16+lr,
  // kv&31 = (i>>2)*16 + lg*4 + (i&3)
  float rwreg[2][8];
#pragma unroll
  for (int qh = 0; qh < 2; ++qh) {
    int wq = qh * 16 + lr;  // q0 % 32 == 0
#pragma unroll
    for (int i = 0; i < 8; ++i) {
      int k = (i >> 2) * 16 + lg * 4 + (i & 3);
      rwreg[qh][i] = rwf[qh * 16 + lr][wq - k + 31];
    }
  }

  f32x4 O[2][4] = {};
  float m[2], l[2];
#pragma unroll
  for (int qh = 0; qh < 2; ++qh) { m[qh] = -1e30f; l[qh] = 0.f; }

  for (int kv0 = 0; kv0 < 1024; kv0 += 64) {
    // ---- QK^T (swapped): st[qh][t][r] = S[kv0+t*16+lg*4+r][q=qh*16+lr] ----
    f32x4 st[2][4];
#pragma unroll
    for (int t = 0; t < 4; ++t) {
      short8 kf0 = *(const short8*)&Kb[(size_t)(kv0 + t * 16 + lr) * 64 + lg * 8];
      short8 kf1 = *(const short8*)&Kb[(size_t)(kv0 + t * 16 + lr) * 64 + 32 + lg * 8];
#pragma unroll
      for (int qh = 0; qh < 2; ++qh) {
        f32x4 z = {};
        z = __builtin_amdgcn_mfma_f32_16x16x32_bf16(kf0, qf[qh][0], z, 0, 0, 0);
        z = __builtin_amdgcn_mfma_f32_16x16x32_bf16(kf1, qf[qh][1], z, 0, 0, 0);
        st[qh][t] = z;
      }
    }
    float alpha[2];
    float p_[2][4][4];
#pragma unroll
    for (int qh = 0; qh < 2; ++qh) {
      float bh0 = rh_lds[qh * 16 + lr][kv0 >> 5];
      float bh1 = rh_lds[qh * 16 + lr][(kv0 >> 5) + 1];
      float mx = -1e30f;
#pragma unroll
      for (int t = 0; t < 4; ++t)
#pragma unroll
        for (int r = 0; r < 4; ++r) {
          float sv = st[qh][t][r] * 0.125f + ((t < 2) ? bh0 : bh1) + rwreg[qh][(t & 1) * 4 + r];
          p_[qh][t][r] = sv;
          mx = fmaxf(mx, sv);
        }
      mx = fmaxf(mx, __shfl_xor(mx, 16, 64));
      mx = fmaxf(mx, __shfl_xor(mx, 32, 64));
      float mnew = fmaxf(m[qh], mx);
      alpha[qh] = __expf(m[qh] - mnew);
      float sm = 0.f;
#pragma unroll
      for (int t = 0; t < 4; ++t)
#pragma unroll
        for (int r = 0; r < 4; ++r) {
          float e = __expf(p_[qh][t][r] - mnew);
          p_[qh][t][r] = e;
          sm += e;
        }
      sm += __shfl_xor(sm, 16, 64);
      sm += __shfl_xor(sm, 32, 64);
      l[qh] = l[qh] * alpha[qh] + sm;
      m[qh] = mnew;
    }
    __syncthreads();  // WAR on pl (and first-iter: rwf alias dead)
#pragma unroll
    for (int qh = 0; qh < 2; ++qh)
#pragma unroll
      for (int t = 0; t < 4; ++t)
#pragma unroll
        for (int h = 0; h < 2; ++h) {
          __hip_bfloat16 b0 = __float2bfloat16(p_[qh][t][2 * h]);
          __hip_bfloat16 b1 = __float2bfloat16(p_[qh][t][2 * h + 1]);
          unsigned u = ((unsigned)*(const unsigned short*)&b1 << 16) |
                       (unsigned)*(const unsigned short*)&b0;
          *(unsigned*)&pl[qh][lr][t * 16 + lg * 4 + 2 * h] = u;
        }
    __syncthreads();
    short8 pf[2][2];
#pragma unroll
    for (int qh = 0; qh < 2; ++qh) {
      pf[qh][0] = *(const short8*)&pl[qh][lr][lg * 8];
      pf[qh][1] = *(const short8*)&pl[qh][lr][32 + lg * 8];
    }
    // O rescale by broadcast alpha (row q'=lg*4+r lives in lane q' of lr-group)
#pragma unroll
    for (int qh = 0; qh < 2; ++qh) {
#pragma unroll
      for (int r = 0; r < 4; ++r) {
        float av = __shfl(alpha[qh], lg * 4 + r, 64);
#pragma unroll
        for (int dt = 0; dt < 4; ++dt) O[qh][dt][r] *= av;
      }
    }
    // ---- PV ----
#pragma unroll
    for (int dt = 0; dt < 4; ++dt) {
      short8 vf0 = *(const short8*)&Vb[(size_t)(dt * 16 + lr) * 1024 + kv0 + lg * 8];
      short8 vf1 = *(const short8*)&Vb[(size_t)(dt * 16 + lr) * 1024 + kv0 + 32 + lg * 8];
#pragma unroll
      for (int qh = 0; qh < 2; ++qh) {
        O[qh][dt] = __builtin_amdgcn_mfma_f32_16x16x32_bf16(pf[qh][0], vf0, O[qh][dt], 0, 0, 0);
        O[qh][dt] = __builtin_amdgcn_mfma_f32_16x16x32_bf16(pf[qh][1], vf1, O[qh][dt], 0, 0, 0);
      }
    }
  }

  // epilogue: faithful out permutation (verified in R0)
#pragma unroll
  for (int qh = 0; qh < 2; ++qh) {
    float linv = 1.f / l[qh];
#pragma unroll
    for (int r = 0; r < 4; ++r) {
      float lv = __shfl(linv, lg * 4 + r, 64);
      int n = q0 + qh * 16 + lg * 4 + r;
#pragma unroll
      for (int dt = 0; dt < 4; ++dt) {
        int d = dt * 16 + lr;
        int Sidx = bh * 65536 + n * 64 + d;
        int b = Sidx / 786432, r1 = Sidx % 786432;
        int pp = r1 / 24576, r2 = r1 % 24576;
        int qq = r2 / 768, r3 = r2 % 768;
        int j = r3 >> 6, dd = r3 & 63;
        int P = b * 786432 + j * 65536 + pp * 2048 + qq * 64 + dd;
        outp[P] = __float2bfloat16(O[qh][dt][r] * lv);
      }
    }
  }
}

extern "C" void kernel_launch(void* const* d_in, const int* in_sizes, int n_in,
                              void* d_out, int out_size, void* d_ws, size_t ws_size,
                              hipStream_t stream) {
  const float* x     = (const float*)d_in[0];
  const float* Wqkv  = (const float*)d_in[1];
  const float* bqkv  = (const float*)d_in[2];
  const float* Wproj = (const float*)d_in[3];
  const float* bproj = (const float*)d_in[4];
  const float* rph   = (const float*)d_in[5];
  const float* rpw   = (const float*)d_in[6];
  float* out = (float*)d_out;
  char* ws = (char*)d_ws;

  __hip_bfloat16* xb     = (__hip_bfloat16*)(ws);
  __hip_bfloat16* wqkvT  = (__hip_bfloat16*)(ws + 12582912);
  __hip_bfloat16* wprojT = (__hip_bfloat16*)(ws + 16121856);
  __hip_bfloat16* qkvb   = (__hip_bfloat16*)(ws + 17301504);  // later aliased as attn-out
  __hip_bfloat16* Qm     = (__hip_bfloat16*)(ws + 55050240);
  __hip_bfloat16* Km     = (__hip_bfloat16*)(ws + 67633152);
  __hip_bfloat16* Vtm    = (__hip_bfloat16*)(ws + 80216064);

  cast_f32_bf16<<<dim3(6144), dim3(256), 0, stream>>>(x, xb);
  transpose_cast<<<dim3(72, 24), dim3(256), 0, stream>>>(Wqkv, wqkvT, 768, 2304);
  transpose_cast<<<dim3(24, 24), dim3(256), 0, stream>>>(Wproj, wprojT, 768, 768);
  gemm_bt<true><<<dim3(18, 64), dim3(256), 0, stream>>>(xb, wqkvT, bqkv, (void*)qkvb, 2304, 768);
  permute_qkv<<<dim3(16, 96), dim3(256), 0, stream>>>(qkvb, Qm, Km, Vtm);
  attn2<<<dim3(3072), dim3(64), 0, stream>>>(Qm, Km, Vtm, rph, rpw, qkvb);
  gemm_bt<false><<<dim3(6, 64), dim3(256), 0, stream>>>(qkvb, wprojT, bproj, (void*)out, 768, 768);
}

// Round 3
// 221.125 us; speedup vs baseline: 2.1777x; 1.1686x over previous
//
#include <hip/hip_runtime.h>
#include <hip/hip_bf16.h>

// Shapes (fixed): B=8, H=W=32, E=768, nh=12, hd=64, N=1024, BH=96
// ws layout (bytes):
//   xb      @ 0          : 12,582,912  (x cast to bf16)
//   wqkvT   @ 12582912   :  3,538,944  (Wqkv^T bf16)
//   wprojT  @ 16121856   :  1,179,648  (Wproj^T bf16)
//   qkvb    @ 17301504   : 37,748,736  (qkv bf16; later aliased by attn-out bf16)
//   Q       @ 55050240   : 12,582,912
//   K       @ 67633152   : 12,582,912
//   Vt      @ 80216064   : 12,582,912  (V transposed: [bh][d][n])

typedef __attribute__((ext_vector_type(8))) short short8;
typedef __attribute__((ext_vector_type(4))) float f32x4;

__global__ __launch_bounds__(256) void cast_f32_bf16(const float* __restrict__ in,
                                                     __hip_bfloat16* __restrict__ out) {
  int i = (blockIdx.x * 256 + threadIdx.x) * 4;
  float4 v = *(const float4*)&in[i];
  out[i + 0] = __float2bfloat16(v.x);
  out[i + 1] = __float2bfloat16(v.y);
  out[i + 2] = __float2bfloat16(v.z);
  out[i + 3] = __float2bfloat16(v.w);
}

// in [K][N] f32 -> out [N][K] bf16
__global__ __launch_bounds__(256) void transpose_cast(const float* __restrict__ in,
                                                      __hip_bfloat16* __restrict__ out,
                                                      int K, int N) {
  __shared__ float tile[32][33];
  int n0 = blockIdx.x * 32, k0 = blockIdx.y * 32;
  int tx = threadIdx.x & 31, ty = threadIdx.x >> 5;  // 32 x 8
#pragma unroll
  for (int i = 0; i < 4; ++i)
    tile[ty + i * 8][tx] = in[(size_t)(k0 + ty + i * 8) * N + n0 + tx];
  __syncthreads();
#pragma unroll
  for (int i = 0; i < 4; ++i)
    out[(size_t)(n0 + ty + i * 8) * K + k0 + tx] = __float2bfloat16(tile[tx][ty + i * 8]);
}

// C[M,N] = A[M,K] * Bt[N,K]^T + bias ; 128x128 tile, 4 waves (2x2), BK=64
template<bool OUT_BF16>
__global__ __launch_bounds__(256) void gemm_bt(const __hip_bfloat16* __restrict__ A,
                                               const __hip_bfloat16* __restrict__ Bt,
                                               const float* __restrict__ bias,
                                               void* __restrict__ Cout,
                                               int N, int K) {
  __shared__ __hip_bfloat16 Al[128][72];
  __shared__ __hip_bfloat16 Bl[128][72];
  int n0 = blockIdx.x * 128, m0 = blockIdx.y * 128;
  int tid = threadIdx.x, lane = tid & 63, wid = tid >> 6;
  int wm = wid >> 1, wn = wid & 1;
  int lr = lane & 15, lg = lane >> 4;
  f32x4 acc[4][4] = {};
  for (int k0 = 0; k0 < K; k0 += 64) {
#pragma unroll
    for (int i = 0; i < 4; ++i) {
      int chunk = tid + 256 * i;
      int row = chunk >> 3, coff = (chunk & 7) * 8;
      *(short8*)&Al[row][coff] = *(const short8*)&A[(size_t)(m0 + row) * K + k0 + coff];
      *(short8*)&Bl[row][coff] = *(const short8*)&Bt[(size_t)(n0 + row) * K + k0 + coff];
    }
    __syncthreads();
#pragma unroll
    for (int ks = 0; ks < 2; ++ks) {
      short8 af[4], bfr[4];
#pragma unroll
      for (int m = 0; m < 4; ++m)
        af[m] = *(const short8*)&Al[wm * 64 + m * 16 + lr][ks * 32 + lg * 8];
#pragma unroll
      for (int n = 0; n < 4; ++n)
        bfr[n] = *(const short8*)&Bl[wn * 64 + n * 16 + lr][ks * 32 + lg * 8];
#pragma unroll
      for (int m = 0; m < 4; ++m)
#pragma unroll
        for (int n = 0; n < 4; ++n)
          acc[m][n] = __builtin_amdgcn_mfma_f32_16x16x32_bf16(af[m], bfr[n], acc[m][n], 0, 0, 0);
    }
    __syncthreads();
  }
#pragma unroll
  for (int n = 0; n < 4; ++n) {
    int col = n0 + wn * 64 + n * 16 + lr;
    float bv = bias[col];
#pragma unroll
    for (int m = 0; m < 4; ++m) {
      int rowb = m0 + wm * 64 + m * 16 + lg * 4;
#pragma unroll
      for (int r = 0; r < 4; ++r) {
        float v = acc[m][n][r] + bv;
        if (OUT_BF16)
          ((__hip_bfloat16*)Cout)[(size_t)(rowb + r) * N + col] = __float2bfloat16(v);
        else
          ((float*)Cout)[(size_t)(rowb + r) * N + col] = v;
      }
    }
  }
}

// Faithful scrambled qkv extraction (verified in R0).
__global__ __launch_bounds__(256) void permute_qkv(const __hip_bfloat16* __restrict__ qkv,
                                                   __hip_bfloat16* __restrict__ Q,
                                                   __hip_bfloat16* __restrict__ Kd,
                                                   __hip_bfloat16* __restrict__ Vt) {
  int bh = blockIdx.y;
  int n0 = blockIdx.x * 64;
  int tid = threadIdx.x;
  __shared__ __hip_bfloat16 vt[64][72];
#pragma unroll
  for (int i = 0; i < 16; ++i) {
    int idx = tid + i * 256;
    int nl = idx >> 6, d2 = idx & 63;
    int n2 = n0 + nl;
    int F = bh * 196608 + n2 * 192 + d2 * 3;
#pragma unroll
    for (int c2 = 0; c2 < 3; ++c2) {
      int Fc = F + c2;
      int b = Fc / 2359296;
      int G = Fc % 2359296;
      int n = G / 2304, G2 = G % 2304;
      int h = G2 / 192, G3 = G2 % 192;
      int c = G3 >> 6, dd = G3 & 63;
      __hip_bfloat16 v = qkv[(size_t)(b * 1024 + n) * 2304 + h * 192 + dd * 3 + c];
      if (c2 == 0)      Q[(size_t)bh * 65536 + n2 * 64 + d2] = v;
      else if (c2 == 1) Kd[(size_t)bh * 65536 + n2 * 64 + d2] = v;
      else              vt[d2][nl] = v;
    }
  }
  __syncthreads();
#pragma unroll
  for (int i = 0; i < 16; ++i) {
    int idx = tid + i * 256;
    int d2 = idx >> 6, nl = idx & 63;
    Vt[(size_t)bh * 65536 + d2 * 1024 + n0 + nl] = vt[d2][nl];
  }
}

__device__ inline short8 cvt8(const float* p) {
  short8 r;
#pragma unroll
  for (int j = 0; j < 8; ++j) {
    __hip_bfloat16 b = __float2bfloat16(p[j]);
    r[j] = *reinterpret_cast<const short*>(&b);
  }
  return r;
}

__device__ inline unsigned pack2(float a, float b) {
  __hip_bfloat16 b0 = __float2bfloat16(a);
  __hip_bfloat16 b1 = __float2bfloat16(b);
  return ((unsigned)*(const unsigned short*)&b1 << 16) |
         (unsigned)*(const unsigned short*)&b0;
}

// Flash attention v3: 1 wave/block, NO barriers (single-wave LDS dataflow is
// ordered by lgkmcnt), defer-max (THR=8, log2 domain) + defer-sum (per-lane
// partial l, reduced once in epilogue), exp2 domain, small LDS (8.8KB).
#define L2E 1.44269504088896f
__global__ __launch_bounds__(64, 4) void attn3(const __hip_bfloat16* __restrict__ Q,
                                               const __hip_bfloat16* __restrict__ Kd,
                                               const __hip_bfloat16* __restrict__ Vt,
                                               const float* __restrict__ rph,
                                               const float* __restrict__ rpw,
                                               __hip_bfloat16* __restrict__ outp) {
  int orig = blockIdx.x;                   // 3072 = 96 bh * 32 qtiles
  int xcd = orig & 7, loc = orig >> 3;     // 384 per xcd
  int bh = xcd * 12 + (loc % 12);
  int qt = loc / 12;                       // 0..31
  int lane = threadIdx.x;
  int lr = lane & 15, lg = lane >> 4;

  __shared__ float rh_lds[32 * 33];        // rh[q_local][kh]*L2E, f32
  __shared__ __hip_bfloat16 smem[2304];    // rwf[32][68] bf16 (prologue) aliased by pl[2][16][72]

  const __hip_bfloat16* Qb = Q + (size_t)bh * 65536;
  const __hip_bfloat16* Kb = Kd + (size_t)bh * 65536;
  const __hip_bfloat16* Vb = Vt + (size_t)bh * 65536;

  int q0 = qt * 32;
  int hq = qt;

  short8 qf[2][2];
#pragma unroll
  for (int qh = 0; qh < 2; ++qh) {
    qf[qh][0] = *(const short8*)&Qb[(size_t)(q0 + qh * 16 + lr) * 64 + lg * 8];
    qf[qh][1] = *(const short8*)&Qb[(size_t)(q0 + qh * 16 + lr) * 64 + 32 + lg * 8];
  }

  // rel-pos bias via MFMA (values pre-scaled by L2E for exp2 domain)
#pragma unroll
  for (int kt = 0; kt < 2; ++kt) {
    int row = hq - (kt * 16 + lr) + 31;  // 0..62
    const float* tp = rph + (size_t)row * 64 + lg * 8;
    short8 th0 = cvt8(tp), th1 = cvt8(tp + 32);
#pragma unroll
    for (int qh = 0; qh < 2; ++qh) {
      f32x4 a = {};
      a = __builtin_amdgcn_mfma_f32_16x16x32_bf16(qf[qh][0], th0, a, 0, 0, 0);
      a = __builtin_amdgcn_mfma_f32_16x16x32_bf16(qf[qh][1], th1, a, 0, 0, 0);
#pragma unroll
      for (int r = 0; r < 4; ++r)
        rh_lds[(qh * 16 + lg * 4 + r) * 33 + kt * 16 + lr] = a[r] * L2E;
    }
  }
#pragma unroll
  for (int jt = 0; jt < 4; ++jt) {
    const float* tp = rpw + (size_t)(jt * 16 + lr) * 64 + lg * 8;
    short8 tw0 = cvt8(tp), tw1 = cvt8(tp + 32);
#pragma unroll
    for (int qh = 0; qh < 2; ++qh) {
      f32x4 a = {};
      a = __builtin_amdgcn_mfma_f32_16x16x32_bf16(qf[qh][0], tw0, a, 0, 0, 0);
      a = __builtin_amdgcn_mfma_f32_16x16x32_bf16(qf[qh][1], tw1, a, 0, 0, 0);
#pragma unroll
      for (int r = 0; r < 4; ++r)
        smem[(qh * 16 + lg * 4 + r) * 68 + jt * 16 + lr] = __float2bfloat16(a[r] * L2E);
    }
  }
  // gather per-lane rw registers (q_local = qh*16+lr; kv&31 = (i>>2)*16+lg*4+(i&3))
  float rwreg[2][8];
#pragma unroll
  for (int qh = 0; qh < 2; ++qh) {
    int wq = qh * 16 + lr;
#pragma unroll
    for (int i = 0; i < 8; ++i) {
      int k = (i >> 2) * 16 + lg * 4 + (i & 3);
      rwreg[qh][i] = __bfloat162float(smem[(qh * 16 + lr) * 68 + (wq - k + 31)]);
    }
  }

  f32x4 O[2][4] = {};
  float m[2] = {-1e30f, -1e30f};
  float lsum[2] = {0.f, 0.f};
  const float C = 0.125f * L2E;

#pragma unroll 1
  for (int kv0 = 0; kv0 < 1024; kv0 += 64) {
    // ---- QK^T (swapped): st[qh][t][r] = S^T, lane holds q-row lr, kv=t*16+lg*4+r
    f32x4 st[2][4];
#pragma unroll
    for (int t = 0; t < 4; ++t) {
      short8 kf0 = *(const short8*)&Kb[(size_t)(kv0 + t * 16 + lr) * 64 + lg * 8];
      short8 kf1 = *(const short8*)&Kb[(size_t)(kv0 + t * 16 + lr) * 64 + 32 + lg * 8];
#pragma unroll
      for (int qh = 0; qh < 2; ++qh) {
        f32x4 z = {};
        z = __builtin_amdgcn_mfma_f32_16x16x32_bf16(kf0, qf[qh][0], z, 0, 0, 0);
        z = __builtin_amdgcn_mfma_f32_16x16x32_bf16(kf1, qf[qh][1], z, 0, 0, 0);
        st[qh][t] = z;
      }
    }
    // ---- bias add (log2 domain) + in-lane max
    int kh = kv0 >> 5;
    float mxl[2];
#pragma unroll
    for (int qh = 0; qh < 2; ++qh) {
      float bh0 = rh_lds[(qh * 16 + lr) * 33 + kh];
      float bh1 = rh_lds[(qh * 16 + lr) * 33 + kh + 1];
      float mx = -1e30f;
#pragma unroll
      for (int t = 0; t < 4; ++t)
#pragma unroll
        for (int r = 0; r < 4; ++r) {
          float sv = fmaf(st[qh][t][r], C, ((t < 2) ? bh0 : bh1) + rwreg[qh][(t & 1) * 4 + r]);
          st[qh][t][r] = sv;
          mx = fmaxf(mx, sv);
        }
      mxl[qh] = mx;
    }
    // ---- defer-max: rescale only when a lane's local max grew past THR
    int cond = (mxl[0] <= m[0] + 8.f) && (mxl[1] <= m[1] + 8.f);
    if (!__all(cond)) {
#pragma unroll
      for (int qh = 0; qh < 2; ++qh) {
        float mx = mxl[qh];
        mx = fmaxf(mx, __shfl_xor(mx, 16, 64));
        mx = fmaxf(mx, __shfl_xor(mx, 32, 64));
        float mnew = fmaxf(m[qh], mx);
        float al = exp2f(m[qh] - mnew);
        lsum[qh] *= al;
        m[qh] = mnew;
#pragma unroll
        for (int r = 0; r < 4; ++r) {
          float av = __shfl(al, lg * 4 + r, 64);
#pragma unroll
          for (int dt = 0; dt < 4; ++dt) O[qh][dt][r] *= av;
        }
      }
    }
    // ---- exp2 + per-lane partial sum + pack to LDS (no barrier: same-wave DS order)
#pragma unroll
    for (int qh = 0; qh < 2; ++qh) {
      float mq = m[qh];
      float sa = 0.f;
#pragma unroll
      for (int t = 0; t < 4; ++t) {
        float p0 = exp2f(st[qh][t][0] - mq);
        float p1 = exp2f(st[qh][t][1] - mq);
        float p2 = exp2f(st[qh][t][2] - mq);
        float p3 = exp2f(st[qh][t][3] - mq);
        sa += (p0 + p1) + (p2 + p3);
        uint2 w;
        w.x = pack2(p0, p1);
        w.y = pack2(p2, p3);
        *(uint2*)&smem[qh * 1152 + lr * 72 + t * 16 + lg * 4] = w;
      }
      lsum[qh] += sa;
    }
    short8 pf[2][2];
#pragma unroll
    for (int qh = 0; qh < 2; ++qh) {
      pf[qh][0] = *(const short8*)&smem[qh * 1152 + lr * 72 + lg * 8];
      pf[qh][1] = *(const short8*)&smem[qh * 1152 + lr * 72 + 32 + lg * 8];
    }
    // ---- PV ----
#pragma unroll
    for (int dt = 0; dt < 4; ++dt) {
      short8 vf0 = *(const short8*)&Vb[(size_t)(dt * 16 + lr) * 1024 + kv0 + lg * 8];
      short8 vf1 = *(const short8*)&Vb[(size_t)(dt * 16 + lr) * 1024 + kv0 + 32 + lg * 8];
#pragma unroll
      for (int qh = 0; qh < 2; ++qh) {
        O[qh][dt] = __builtin_amdgcn_mfma_f32_16x16x32_bf16(pf[qh][0], vf0, O[qh][dt], 0, 0, 0);
        O[qh][dt] = __builtin_amdgcn_mfma_f32_16x16x32_bf16(pf[qh][1], vf1, O[qh][dt], 0, 0, 0);
      }
    }
  }

  // epilogue: reduce deferred l, then faithful out permutation (verified in R0)
#pragma unroll
  for (int qh = 0; qh < 2; ++qh) {
    float lt = lsum[qh];
    lt += __shfl_xor(lt, 16, 64);
    lt += __shfl_xor(lt, 32, 64);
    float linv = 1.f / lt;
#pragma unroll
    for (int r = 0; r < 4; ++r) {
      float lv = __shfl(linv, lg * 4 + r, 64);
      int n = q0 + qh * 16 + lg * 4 + r;
#pragma unroll
      for (int dt = 0; dt < 4; ++dt) {
        int d = dt * 16 + lr;
        int Sidx = bh * 65536 + n * 64 + d;
        int b = Sidx / 786432, r1 = Sidx % 786432;
        int pp = r1 / 24576, r2 = r1 % 24576;
        int qq = r2 / 768, r3 = r2 % 768;
        int j = r3 >> 6, dd = r3 & 63;
        int P = b * 786432 + j * 65536 + pp * 2048 + qq * 64 + dd;
        outp[P] = __float2bfloat16(O[qh][dt][r] * lv);
      }
    }
  }
}

extern "C" void kernel_launch(void* const* d_in, const int* in_sizes, int n_in,
                              void* d_out, int out_size, void* d_ws, size_t ws_size,
                              hipStream_t stream) {
  const float* x     = (const float*)d_in[0];
  const float* Wqkv  = (const float*)d_in[1];
  const float* bqkv  = (const float*)d_in[2];
  const float* Wproj = (const float*)d_in[3];
  const float* bproj = (const float*)d_in[4];
  const float* rph   = (const float*)d_in[5];
  const float* rpw   = (const float*)d_in[6];
  float* out = (float*)d_out;
  char* ws = (char*)d_ws;

  __hip_bfloat16* xb     = (__hip_bfloat16*)(ws);
  __hip_bfloat16* wqkvT  = (__hip_bfloat16*)(ws + 12582912);
  __hip_bfloat16* wprojT = (__hip_bfloat16*)(ws + 16121856);
  __hip_bfloat16* qkvb   = (__hip_bfloat16*)(ws + 17301504);  // later aliased as attn-out
  __hip_bfloat16* Qm     = (__hip_bfloat16*)(ws + 55050240);
  __hip_bfloat16* Km     = (__hip_bfloat16*)(ws + 67633152);
  __hip_bfloat16* Vtm    = (__hip_bfloat16*)(ws + 80216064);

  cast_f32_bf16<<<dim3(6144), dim3(256), 0, stream>>>(x, xb);
  transpose_cast<<<dim3(72, 24), dim3(256), 0, stream>>>(Wqkv, wqkvT, 768, 2304);
  transpose_cast<<<dim3(24, 24), dim3(256), 0, stream>>>(Wproj, wprojT, 768, 768);
  gemm_bt<true><<<dim3(18, 64), dim3(256), 0, stream>>>(xb, wqkvT, bqkv, (void*)qkvb, 2304, 768);
  permute_qkv<<<dim3(16, 96), dim3(256), 0, stream>>>(qkvb, Qm, Km, Vtm);
  attn3<<<dim3(3072), dim3(64), 0, stream>>>(Qm, Km, Vtm, rph, rpw, qkvb);
  gemm_bt<false><<<dim3(6, 64), dim3(256), 0, stream>>>(qkvb, wprojT, bproj, (void*)out, 768, 768);
}